// Round 13
// baseline (161.493 us; speedup 1.0000x reference)
//
#include <hip/hip_runtime.h>
#include <math.h>

#define DD    128
#define DI    170
#define DIP   176            // padded i-dimension (cols 170..175 zero)
#define ND4   32             // DD/4 d-chunks
#define NI4P  44             // padded i4 chunk count (chunk 42 half, 43 zero)
#define BB    4096
#define NNEG  5
#define RPW   2              // rows per wave
#define WPB   4              // waves per block (256 threads)
#define ROWSB (RPW * WPB)    // 8 rows per block
#define NBLK  (BB / ROWSB)   // 512 blocks -> 2 blocks/CU, 8 waves/CU
#define NTHR  (WPB * 64)
#define SQRT_D 11.3137084989847603904f   // sqrt(128)

// workspace layout (floats)
#define WS_WHT 0                          // [32][176] float4
#define WS_WGT (ND4 * DIP * 4)            // 22528 floats
#define WS_WFT (2 * ND4 * DIP * 4)        // 45056 floats; [44][128] float4

#define DOT4(a, b) ((a).x * (b).x + (a).y * (b).y + (a).z * (b).z + (a).w * (b).w)

__device__ __forceinline__ float wave_bcast_sum(float v) {
#pragma unroll
    for (int m = 1; m < 64; m <<= 1) v += __shfl_xor(v, m, 64);
    return v;
}

// Prep: per-call recompute of normalized+scale-folded TRANSPOSED weights into ws.
//  whT4[d4][i]  = W_hidden[i][4d4+c] * inv_h[i]*hidden_scale[i]*inv_f[i]
//  wgT4[d4][i]  = W_gate  [i][4d4+c] * inv_g[i]*gate_scale[i]*sqrt(D)
//  wfT4[i4][dd] = W_ff_out[dd][4i4+c]  (raw; col-norms folded via whT)
__global__ __launch_bounds__(256) void prep_kernel(
    const float* __restrict__ W_hidden,
    const float* __restrict__ W_gate,
    const float* __restrict__ W_ff_out,
    const float* __restrict__ hidden_scale,
    const float* __restrict__ gate_scale,
    float* __restrict__ ws,
    float* __restrict__ out)
{
    if (blockIdx.x == 0 && threadIdx.x == 0) out[0] = 0.0f;
    const int wave = threadIdx.x >> 6;
    const int lane = threadIdx.x & 63;
    const int t = blockIdx.x * 4 + wave;
    float* whT = ws + WS_WHT;
    float* wgT = ws + WS_WGT;
    float* wfT = ws + WS_WFT;

    if (t < DI) {
        const int v = t;
        // inverse norm of W_ff_out column v (128 entries, stride DI)
        float a = W_ff_out[(long)(2 * lane)     * DI + v];
        float b = W_ff_out[(long)(2 * lane + 1) * DI + v];
        float cf = wave_bcast_sum(a * a + b * b);
        // row norms of W_hidden / W_gate row v
        float2 ph = ((const float2*)(W_hidden + (long)v * DD))[lane];
        float2 pg = ((const float2*)(W_gate   + (long)v * DD))[lane];
        float sh = wave_bcast_sum(ph.x * ph.x + ph.y * ph.y);
        float sg = wave_bcast_sum(pg.x * pg.x + pg.y * pg.y);
        const float whs = rsqrtf(sh) * hidden_scale[v] * rsqrtf(cf);
        const float wgs = rsqrtf(sg) * gate_scale[v] * SQRT_D;
        // transposed write: lane holds d = 2*lane, 2*lane+1 -> d4 = lane>>1
        const int d4   = lane >> 1;
        const int half = lane & 1;                  // 0: comps {0,1}, 1: comps {2,3}
        float2* dh = (float2*)(whT + ((long)d4 * DIP + v) * 4 + half * 2);
        *dh = make_float2(ph.x * whs, ph.y * whs);
        float2* dg = (float2*)(wgT + ((long)d4 * DIP + v) * 4 + half * 2);
        *dg = make_float2(pg.x * wgs, pg.y * wgs);
    } else if (t < DI + NI4P) {
        const int i4 = t - DI;                      // 0..43
#pragma unroll
        for (int rr = 0; rr < 2; ++rr) {
            const int dd = rr * 64 + lane;
            float4 v4;
            if (i4 < 42) {   // rows are 8B-aligned (680B): use two float2 loads
                float2 lo = *(const float2*)(W_ff_out + (long)dd * DI + 4 * i4);
                float2 hi = *(const float2*)(W_ff_out + (long)dd * DI + 4 * i4 + 2);
                v4 = make_float4(lo.x, lo.y, hi.x, hi.y);
            } else if (i4 == 42) {  // i = 168,169 valid; 170,171 zero-pad
                float2 lo = *(const float2*)(W_ff_out + (long)dd * DI + 168);
                v4 = make_float4(lo.x, lo.y, 0.0f, 0.0f);
            } else {                // i4 == 43: all pad
                v4 = make_float4(0.0f, 0.0f, 0.0f, 0.0f);
            }
            *(float4*)(wfT + ((long)i4 * DD + dd) * 4) = v4;
        }
    } else if (t == DI + NI4P || t == DI + NI4P + 1) {
        // zero pad columns 170..175 of whT / wgT
        float* base = (t == DI + NI4P) ? whT : wgT;
        for (int idx = lane; idx < ND4 * 6; idx += 64) {
            const int d4 = idx / 6, c = idx % 6;
            *(float4*)(base + ((long)d4 * DIP + DI + c) * 4) =
                make_float4(0.0f, 0.0f, 0.0f, 0.0f);
        }
    }
}

// Wave-autonomous main kernel: each wave computes RPW=2 rows end-to-end with
// NO block-level barriers (waves stall independently; co-resident waves fill
// each other's bubbles). All weight reads are lane-consecutive float4
// (coalesced); emb/x broadcasts go through wave-PRIVATE LDS slices whose
// RAW hazards are ordered by the compiler's own lgkmcnt waits.
__global__ __launch_bounds__(NTHR, 2) void main_kernel(
    const int*   __restrict__ input_ids,
    const int*   __restrict__ target_ids,
    const int*   __restrict__ neg_ids,
    const float* __restrict__ W_in,
    const float* __restrict__ W_out,
    const float* __restrict__ logit_scale,
    const float* __restrict__ ws,
    float* __restrict__ out)
{
    __shared__ __align__(16) float s_emb[WPB][RPW][DD];   // 4 KB, wave-private slices
    __shared__ __align__(16) float s_x[WPB][RPW][DIP];    // 5.5 KB, wave-private
    __shared__ float s_red[WPB];

    const int tid  = threadIdx.x;
    const int wave = tid >> 6;
    const int lane = tid & 63;
    const int rb   = blockIdx.x * ROWSB + wave * RPW;     // this wave's first row

    const float4* whT4 = (const float4*)(ws + WS_WHT);    // [32][176]
    const float4* wgT4 = (const float4*)(ws + WS_WGT);
    const float4* wfT4 = (const float4*)(ws + WS_WFT);    // [44][128]

    // ---- Step 1: gather + l2-normalize this wave's 2 embeddings ----
#pragma unroll
    for (int rr = 0; rr < RPW; ++rr) {
        const int id = input_ids[rb + rr];
        float2 p = ((const float2*)(W_in + (long)id * DD))[lane];
        float s  = wave_bcast_sum(p.x * p.x + p.y * p.y);
        float inv = rsqrtf(s);
        s_emb[wave][rr][2 * lane]     = p.x * inv;
        s_emb[wave][rr][2 * lane + 1] = p.y * inv;
    }
    // (wave-internal RAW: compiler emits lgkmcnt wait; no barrier needed)

    // ---- Step 2: h,g for 2 rows. Lane owns cols {lane, lane+64, lane+128}
    //      (<176). Weight reads lane-consecutive -> coalesced 1KB/instr. ----
    float ah[RPW][3], ag[RPW][3];
#pragma unroll
    for (int rr = 0; rr < RPW; ++rr)
#pragma unroll
        for (int c = 0; c < 3; ++c) { ah[rr][c] = 0.0f; ag[rr][c] = 0.0f; }

#pragma unroll 4
    for (int d4 = 0; d4 < ND4; ++d4) {
        float4 e0 = ((const float4*)s_emb[wave][0])[d4];   // uniform: broadcast
        float4 e1 = ((const float4*)s_emb[wave][1])[d4];
#pragma unroll
        for (int c = 0; c < 3; ++c) {
            const int ic = lane + 64 * c;
            if (ic < DIP) {
                float4 h4 = whT4[d4 * DIP + ic];
                float4 g4 = wgT4[d4 * DIP + ic];
                ah[0][c] += DOT4(e0, h4);
                ah[1][c] += DOT4(e1, h4);
                ag[0][c] += DOT4(e0, g4);
                ag[1][c] += DOT4(e1, g4);
            }
        }
    }

    // ---- Step 3: silu -> x into wave-private LDS (scales folded in prep) ----
#pragma unroll
    for (int c = 0; c < 3; ++c) {
        const int ic = lane + 64 * c;
        if (ic < DIP) {
#pragma unroll
            for (int rr = 0; rr < RPW; ++rr) {
                float h = ah[rr][c];
                float g = ag[rr][c];
                s_x[wave][rr][ic] = (g / (1.0f + __expf(-g))) * h;  // pad cols -> 0
            }
        }
    }

    // ---- Step 4: xout stays in REGISTERS: lane owns dd=lane and dd=lane+64.
    //      acc[rr][0] = xout[rr][lane], acc[rr][1] = xout[rr][64+lane] ----
    float acc[RPW][2];
#pragma unroll
    for (int rr = 0; rr < RPW; ++rr) { acc[rr][0] = 0.0f; acc[rr][1] = 0.0f; }
#pragma unroll 4
    for (int i4 = 0; i4 < NI4P; ++i4) {
        float4 x0 = ((const float4*)s_x[wave][0])[i4];     // uniform: broadcast
        float4 x1 = ((const float4*)s_x[wave][1])[i4];
        float4 wa = wfT4[i4 * DD + lane];                  // coalesced
        float4 wb = wfT4[i4 * DD + 64 + lane];
        acc[0][0] += DOT4(x0, wa);
        acc[0][1] += DOT4(x0, wb);
        acc[1][0] += DOT4(x1, wa);
        acc[1][1] += DOT4(x1, wb);
    }

    // ---- Step 5: 12 logit tasks (2 rows x 6). Ids/scales via lane<12 gather
    //      + shfl broadcast; all 24 W_out row-loads issued before reducing. ----
    int   myid  = 0;
    float mypsc = 0.0f;
    if (lane < 2 * (1 + NNEG)) {
        const int t  = lane;
        const int rr = t / (1 + NNEG);
        const int jj = t % (1 + NNEG);
        const int bidx = rb + rr;
        myid  = (jj == 0) ? target_ids[bidx] : neg_ids[bidx * NNEG + jj - 1];
        mypsc = logit_scale[myid];
    }
    float w0a[12], w1a[12];
#pragma unroll
    for (int t = 0; t < 12; ++t) {
        const int idt = __shfl(myid, t, 64);
        const float* wrow = W_out + (long)idt * DD;
        w0a[t] = wrow[lane];
        w1a[t] = wrow[64 + lane];
    }
    float wacc = 0.0f;
#pragma unroll
    for (int t = 0; t < 12; ++t) {
        const int rr = t / (1 + NNEG);
        const int jj = t % (1 + NNEG);
        float dot = w0a[t] * acc[rr][0] + w1a[t] * acc[rr][1];
        float ss  = w0a[t] * w0a[t] + w1a[t] * w1a[t];
#pragma unroll
        for (int m = 1; m < 64; m <<= 1) {
            dot += __shfl_xor(dot, m, 64);
            ss  += __shfl_xor(ss,  m, 64);
        }
        const float psc = __shfl(mypsc, t, 64);
        const float logit = dot * rsqrtf(ss) * psc * SQRT_D;
        const float z  = (jj == 0) ? logit : -logit;
        const float ls = fminf(z, 0.0f) - log1pf(__expf(-fabsf(z)));   // stable log_sigmoid
        wacc += (jj == 0) ? ls * (1.0f / BB) : ls * (1.0f / (BB * NNEG));
    }
    if (lane == 0) s_red[wave] = wacc;
    __syncthreads();               // the ONLY block barrier
    if (tid == 0) {
        float tot = s_red[0] + s_red[1] + s_red[2] + s_red[3];
        atomicAdd(out, -tot);
    }
}

extern "C" void kernel_launch(void* const* d_in, const int* in_sizes, int n_in,
                              void* d_out, int out_size, void* d_ws, size_t ws_size,
                              hipStream_t stream) {
    (void)in_sizes; (void)n_in; (void)out_size; (void)ws_size;
    const int*   input_ids    = (const int*)  d_in[0];
    const int*   target_ids   = (const int*)  d_in[1];
    const int*   neg_ids      = (const int*)  d_in[2];
    const float* W_in         = (const float*)d_in[3];
    const float* W_out        = (const float*)d_in[4];
    const float* W_hidden     = (const float*)d_in[5];
    const float* W_gate       = (const float*)d_in[6];
    const float* W_ff_out     = (const float*)d_in[7];
    const float* hidden_scale = (const float*)d_in[8];
    const float* gate_scale   = (const float*)d_in[9];
    const float* logit_scale  = (const float*)d_in[10];
    float* out = (float*)d_out;
    float* ws  = (float*)d_ws;     // needs 270 KB

    prep_kernel<<<54, 256, 0, stream>>>(W_hidden, W_gate, W_ff_out,
                                        hidden_scale, gate_scale, ws, out);
    main_kernel<<<NBLK, NTHR, 0, stream>>>(input_ids, target_ids, neg_ids,
                                           W_in, W_out, logit_scale, ws, out);
}

// Round 14
// 151.746 us; speedup vs baseline: 1.0642x; 1.0642x over previous
//
#include <hip/hip_runtime.h>
#include <math.h>

#define DD    128
#define DI    170
#define DIP   176            // padded i-dimension (zero pad cols 170..175)
#define ND4   32             // DD/4 d-chunks
#define ND4H  16             // half of ND4 (split-d)
#define NI4P  44             // padded i4 chunk count (chunk 42 half, 43 zero)
#define BB    4096
#define NNEG  5
#define ROWS  8
#define NBLK  (BB / ROWS)    // 512 blocks -> 2 blocks/CU
#define NTHR  1024           // 16 waves/block -> 32 waves/CU (8/SIMD)
#define NTASK (ROWS * (1 + NNEG))   // 48 gather tasks
#define XOP   132            // padded s_xout row stride (floats)
#define SQRT_D 11.3137084989847603904f   // sqrt(128)

// workspace layout (floats)
#define WS_WHT 0                          // [32][176] float4
#define WS_WGT (ND4 * DIP * 4)            // 22528 floats
#define WS_WFT (2 * ND4 * DIP * 4)        // 45056 floats; [44][128] float4

// barrier that orders LDS only (no global_load_lds DMA anywhere in this
// kernel, so vmcnt never needs draining at a barrier; per-wave register
// loads are ordered by the compiler's own vmcnt waits before use).
#define BAR_LGKM() asm volatile("s_waitcnt lgkmcnt(0)\n\ts_barrier" ::: "memory")

#define DOT4(a, b) ((a).x * (b).x + (a).y * (b).y + (a).z * (b).z + (a).w * (b).w)

__device__ __forceinline__ float wave_bcast_sum(float v) {
#pragma unroll
    for (int m = 1; m < 64; m <<= 1) v += __shfl_xor(v, m, 64);
    return v;
}

// Prep: per-call recompute of normalized+scale-folded TRANSPOSED weights into ws.
//  whT4[d4][i]  = W_hidden[i][4d4+c] * inv_h[i]*hidden_scale[i]*inv_f[i]
//  wgT4[d4][i]  = W_gate  [i][4d4+c] * inv_g[i]*gate_scale[i]*sqrt(D)
//  wfT4[i4][dd] = W_ff_out[dd][4i4+c]  (raw; col-norms folded via whT)
__global__ __launch_bounds__(256) void prep_kernel(
    const float* __restrict__ W_hidden,
    const float* __restrict__ W_gate,
    const float* __restrict__ W_ff_out,
    const float* __restrict__ hidden_scale,
    const float* __restrict__ gate_scale,
    float* __restrict__ ws,
    float* __restrict__ out)
{
    if (blockIdx.x == 0 && threadIdx.x == 0) out[0] = 0.0f;
    const int wave = threadIdx.x >> 6;
    const int lane = threadIdx.x & 63;
    const int t = blockIdx.x * 4 + wave;
    float* whT = ws + WS_WHT;
    float* wgT = ws + WS_WGT;
    float* wfT = ws + WS_WFT;

    if (t < DI) {
        const int v = t;
        // inverse norm of W_ff_out column v (128 entries, stride DI)
        float a = W_ff_out[(long)(2 * lane)     * DI + v];
        float b = W_ff_out[(long)(2 * lane + 1) * DI + v];
        float cf = wave_bcast_sum(a * a + b * b);
        // row norms of W_hidden / W_gate row v
        float2 ph = ((const float2*)(W_hidden + (long)v * DD))[lane];
        float2 pg = ((const float2*)(W_gate   + (long)v * DD))[lane];
        float sh = wave_bcast_sum(ph.x * ph.x + ph.y * ph.y);
        float sg = wave_bcast_sum(pg.x * pg.x + pg.y * pg.y);
        const float whs = rsqrtf(sh) * hidden_scale[v] * rsqrtf(cf);
        const float wgs = rsqrtf(sg) * gate_scale[v] * SQRT_D;
        // transposed write: lane holds d = 2*lane, 2*lane+1 -> d4 = lane>>1
        const int d4   = lane >> 1;
        const int half = lane & 1;                  // 0: comps {0,1}, 1: comps {2,3}
        float2* dh = (float2*)(whT + ((long)d4 * DIP + v) * 4 + half * 2);
        *dh = make_float2(ph.x * whs, ph.y * whs);
        float2* dg = (float2*)(wgT + ((long)d4 * DIP + v) * 4 + half * 2);
        *dg = make_float2(pg.x * wgs, pg.y * wgs);
    } else if (t < DI + NI4P) {
        const int i4 = t - DI;                      // 0..43
#pragma unroll
        for (int rr = 0; rr < 2; ++rr) {
            const int dd = rr * 64 + lane;
            float4 v4;
            if (i4 < 42) {   // rows are 8B-aligned (680B): use two float2 loads
                float2 lo = *(const float2*)(W_ff_out + (long)dd * DI + 4 * i4);
                float2 hi = *(const float2*)(W_ff_out + (long)dd * DI + 4 * i4 + 2);
                v4 = make_float4(lo.x, lo.y, hi.x, hi.y);
            } else if (i4 == 42) {  // i = 168,169 valid; 170,171 zero-pad
                float2 lo = *(const float2*)(W_ff_out + (long)dd * DI + 168);
                v4 = make_float4(lo.x, lo.y, 0.0f, 0.0f);
            } else {                // i4 == 43: all pad
                v4 = make_float4(0.0f, 0.0f, 0.0f, 0.0f);
            }
            *(float4*)(wfT + ((long)i4 * DD + dd) * 4) = v4;
        }
    } else if (t == DI + NI4P || t == DI + NI4P + 1) {
        // zero pad columns 170..175 of whT / wgT
        float* base = (t == DI + NI4P) ? whT : wgT;
        for (int idx = lane; idx < ND4 * 6; idx += 64) {
            const int d4 = idx / 6, c = idx % 6;
            *(float4*)(base + ((long)d4 * DIP + DI + c) * 4) =
                make_float4(0.0f, 0.0f, 0.0f, 0.0f);
        }
    }
}

// 1024-thread main kernel: same per-block tile (8 rows, weights streamed once)
// as the previous 512-thread version, but 32 waves/CU (8/SIMD) for 2x the
// latency-hiding at identical traffic. All accumulation orders bit-identical:
//  - P2: h = (d4 0..15) + (d4 16..31), g likewise; four 176-thread quarters
//  - P2b: per-(q,dd) row sums over i4 in [11q,11q+11); rows split over halves
//  - xout: ((q0+q1)+q2)+q3 ;  P3: chunked dot/ss with c-fold
__global__ __launch_bounds__(NTHR, 8) void main_kernel(
    const int*   __restrict__ input_ids,
    const int*   __restrict__ target_ids,
    const int*   __restrict__ neg_ids,
    const float* __restrict__ W_in,
    const float* __restrict__ W_out,
    const float* __restrict__ logit_scale,
    const float* __restrict__ ws,
    float* __restrict__ out)
{
    __shared__ __align__(16) float s_emb[ROWS][DD];    // 4 KB
    __shared__ __align__(16) float s_x[ROWS][DIP];     // 5.5 KB
    __shared__ __align__(16) float s_pp[4][ROWS][DD];  // 16 KB: 2b 4-slice partials
    __shared__ __align__(16) float s_xout[ROWS][XOP];  // 4.125 KB (132-pad)
    __shared__ float s_part[DIP][25];                  // 17.6 KB: P2 partials (hhi,glo,ghi)
    __shared__ float s_dp[NTASK][9];                   // P3 dot partials
    __shared__ float s_sp[NTASK][9];                   // P3 |w|^2 partials
    __shared__ float s_psc[NTASK];                     // logit_scale[id]
    __shared__ float s_ls[NTASK];                      // weighted log-sigmoid

    const int tid  = threadIdx.x;
    const int wave = tid >> 6;
    const int lane = tid & 63;
    const int b0   = blockIdx.x * ROWS;

    const float4* whT4 = (const float4*)(ws + WS_WHT);  // [32][176]
    const float4* wgT4 = (const float4*)(ws + WS_WGT);
    const float4* wfT4 = (const float4*)(ws + WS_WFT);  // [44][128]

    // ---- Phase 1: gather + l2-normalize embeddings; wave w (<8) -> row w ----
    if (wave < ROWS) {
        const int id = input_ids[b0 + wave];
        float2 p = ((const float2*)(W_in + (long)id * DD))[lane];
        float s  = wave_bcast_sum(p.x * p.x + p.y * p.y);
        float inv = rsqrtf(s);
        s_emb[wave][2 * lane]     = p.x * inv;
        s_emb[wave][2 * lane + 1] = p.y * inv;
    }
    BAR_LGKM();

    // ---- Phase 2: four 176-thread quarters, each 8 d4-chunks of one matrix:
    //      q0=(h,dlo) q1=(h,dhi) q2=(g,dlo) q3=(g,dhi). Quarter 0 merges. ----
    const int quarter = tid >> 8;                 // 0..3
    const int qi      = tid & 255;                // index within quarter
    float a[ROWS];
#pragma unroll
    for (int r = 0; r < ROWS; ++r) a[r] = 0.0f;

    if (qi < DIP) {
        const float4* wT  = (quarter < 2) ? whT4 : wgT4;
        const int d4lo    = (quarter & 1) * ND4H;
#pragma unroll 4
        for (int k = 0; k < ND4H; ++k) {
            const int d4 = d4lo + k;
            float4 w4 = wT[d4 * DIP + qi];        // lane-consecutive: coalesced
#pragma unroll
            for (int r = 0; r < ROWS; ++r) {
                float4 e4 = ((const float4*)s_emb[r])[d4];   // uniform: broadcast
                a[r] += DOT4(e4, w4);
            }
        }
        if (quarter > 0) {
#pragma unroll
            for (int r = 0; r < ROWS; ++r)
                s_part[qi][(quarter - 1) * ROWS + r] = a[r];
        }
    }
    BAR_LGKM();

    if (quarter == 0 && qi < DIP) {
#pragma unroll
        for (int r = 0; r < ROWS; ++r) {
            float h = a[r] + s_part[qi][r];                    // (dlo)+(dhi)
            float g = s_part[qi][ROWS + r] + s_part[qi][2 * ROWS + r];
            float x = (g / (1.0f + __expf(-g))) * h;           // silu(g) * h
            s_x[r][qi] = x;                                    // pad cols -> 0
        }
    }
    BAR_LGKM();

    // ---- Phase 2b: (q, dd, row-half): q = (tid>>7)&3 owns i4 in [11q,11q+11),
    //      rh = tid>>9 owns rows rh*4..rh*4+3. Per-row sums identical to the
    //      512-thread version (rows are independent accumulators). ----
    {
        const int dd = tid & 127;
        const int q  = (tid >> 7) & 3;
        const int rh = tid >> 9;                  // 0 or 1
        const int i4lo = q * 11;
        float acc[4];
#pragma unroll
        for (int rr = 0; rr < 4; ++rr) acc[rr] = 0.0f;
#pragma unroll 4
        for (int k = 0; k < 11; ++k) {
            const int i4 = i4lo + k;
            float4 w4 = wfT4[i4 * DD + dd];       // coalesced (L1-shared across rh)
#pragma unroll
            for (int rr = 0; rr < 4; ++rr) {
                const int r = rh * 4 + rr;
                float4 x4 = ((const float4*)s_x[r])[i4];     // uniform: broadcast
                acc[rr] += w4.x * x4.x + w4.y * x4.y + w4.z * x4.z + w4.w * x4.w;
            }
        }
#pragma unroll
        for (int rr = 0; rr < 4; ++rr) s_pp[q][rh * 4 + rr][dd] = acc[rr];
    }
    BAR_LGKM();

    // ---- materialize xout: fixed 4-term fold; (r,dd) = (tid>>7, tid&127) ----
    {
        const int dd = tid & 127;
        const int r  = tid >> 7;                  // 0..7
        float v = ((s_pp[0][r][dd] + s_pp[1][r][dd])
                   + s_pp[2][r][dd]) + s_pp[3][r][dd];
        s_xout[r][dd] = v;
    }
    BAR_LGKM();

    // ---- Phase 3a: DATA-PARALLEL logits; 8 threads/task, direct W_out reads ----
    if (tid < NTASK * 8) {
        const int t  = tid >> 3;                  // 0..47
        const int c  = tid & 7;                   // 0..7
        const int r  = t / (1 + NNEG);
        const int jj = t % (1 + NNEG);
        const int bidx = b0 + r;
        const int id = (jj == 0) ? target_ids[bidx] : neg_ids[bidx * NNEG + jj - 1];
        if (c == 0) s_psc[t] = logit_scale[id];
        const float4* wrow4 = (const float4*)(W_out + (long)id * DD);
        const float4* xr4   = (const float4*)&s_xout[r][0];
        float dot = 0.0f, ss = 0.0f;
#pragma unroll
        for (int k2 = 0; k2 < 4; ++k2) {
            const int j = c + 8 * k2;
            float4 w4 = wrow4[j];
            float4 x4 = xr4[j];
            dot += w4.x * x4.x + w4.y * x4.y + w4.z * x4.z + w4.w * x4.w;
            ss  += w4.x * w4.x + w4.y * w4.y + w4.z * w4.z + w4.w * w4.w;
        }
        s_dp[t][c] = dot;
        s_sp[t][c] = ss;
    }
    BAR_LGKM();

    // ---- Phase 3b: per-task fold (fixed order) + log-sigmoid ----
    if (tid < NTASK) {
        const int t  = tid;
        const int jj = t % (1 + NNEG);
        float dot = s_dp[t][0], ss = s_sp[t][0];
#pragma unroll
        for (int c = 1; c < 8; ++c) { dot += s_dp[t][c]; ss += s_sp[t][c]; }
        const float logit = dot * rsqrtf(ss) * s_psc[t] * SQRT_D;
        const float z  = (jj == 0) ? logit : -logit;
        const float ls = fminf(z, 0.0f) - log1pf(__expf(-fabsf(z)));   // stable log_sigmoid
        s_ls[t] = (jj == 0) ? ls * (1.0f / BB) : ls * (1.0f / (BB * NNEG));
    }
    BAR_LGKM();
    if (tid == 0) {
        float tot = 0.0f;
#pragma unroll
        for (int t = 0; t < NTASK; ++t) tot += s_ls[t];
        atomicAdd(out, -tot);
    }
}

extern "C" void kernel_launch(void* const* d_in, const int* in_sizes, int n_in,
                              void* d_out, int out_size, void* d_ws, size_t ws_size,
                              hipStream_t stream) {
    (void)in_sizes; (void)n_in; (void)out_size; (void)ws_size;
    const int*   input_ids    = (const int*)  d_in[0];
    const int*   target_ids   = (const int*)  d_in[1];
    const int*   neg_ids      = (const int*)  d_in[2];
    const float* W_in         = (const float*)d_in[3];
    const float* W_out        = (const float*)d_in[4];
    const float* W_hidden     = (const float*)d_in[5];
    const float* W_gate       = (const float*)d_in[6];
    const float* W_ff_out     = (const float*)d_in[7];
    const float* hidden_scale = (const float*)d_in[8];
    const float* gate_scale   = (const float*)d_in[9];
    const float* logit_scale  = (const float*)d_in[10];
    float* out = (float*)d_out;
    float* ws  = (float*)d_ws;     // needs 270 KB

    prep_kernel<<<54, 256, 0, stream>>>(W_hidden, W_gate, W_ff_out,
                                        hidden_scale, gate_scale, ws, out);
    main_kernel<<<NBLK, NTHR, 0, stream>>>(input_ids, target_ids, neg_ids,
                                           W_in, W_out, logit_scale, ws, out);
}